// Round 9
// baseline (3366.911 us; speedup 1.0000x reference)
//
#include <hip/hip_runtime.h>
#include <cstdint>
#include <cstddef>

// Problem constants
#define TT 8
#define NN 20000
#define FIN 128
#define HH 128
#define NHEADS 4
#define DD 32
#define RR 12
#define EE 40000
#define LL 2
#define CC 16
#define RN (RR*NN)        // 240000 segments (relation, dst-node)
#define RE (RR*EE)        // 480000 edges total
#define TNH ((size_t)TT*NN*HH)   // 20.48M floats per type-space tensor

struct Job { const float* in; const float* w; const float* b; float* out; };
struct Jobs8  { Job j[8]; };
struct Jobs16 { Job j[16]; };

// ---------------------------------------------------------------------------
// zero fill (avoids hipMemsetAsync in the capture path)
// ---------------------------------------------------------------------------
__global__ __launch_bounds__(256) void zero_kernel(float4* __restrict__ p, int n4) {
    int i = blockIdx.x * 256 + threadIdx.x;
    int stride = gridDim.x * 256;
    for (; i < n4; i += stride) p[i] = make_float4(0.f, 0.f, 0.f, 0.f);
}

// ---------------------------------------------------------------------------
// CSR build: histogram -> scan -> scatter (keyed by r*N + edge_dst)
// ---------------------------------------------------------------------------
__global__ __launch_bounds__(256) void hist_kernel(const int* __restrict__ edge_dst,
                                                   int* __restrict__ cnt) {
    int g = blockIdx.x * 256 + threadIdx.x;
    if (g < RE) {
        int r = g / EE;
        atomicAdd(&cnt[r * NN + edge_dst[g]], 1);
    }
}

__global__ __launch_bounds__(256) void scan_local(const int* __restrict__ in,
                                                  int* __restrict__ out,
                                                  int* __restrict__ bsum, int n) {
    __shared__ int sh[256];
    int t = threadIdx.x;
    int base = blockIdx.x * 1024 + t * 4;
    int v0 = (base + 0 < n) ? in[base + 0] : 0;
    int v1 = (base + 1 < n) ? in[base + 1] : 0;
    int v2 = (base + 2 < n) ? in[base + 2] : 0;
    int v3 = (base + 3 < n) ? in[base + 3] : 0;
    int s = v0 + v1 + v2 + v3;
    sh[t] = s;
    __syncthreads();
    for (int off = 1; off < 256; off <<= 1) {
        int tmp = (t >= off) ? sh[t - off] : 0;
        __syncthreads();
        sh[t] += tmp;
        __syncthreads();
    }
    int incl = sh[t];
    int e = incl - s;                 // exclusive prefix of this thread's chunk
    if (t == 255) bsum[blockIdx.x] = incl;
    if (base + 0 < n) out[base + 0] = e; e += v0;
    if (base + 1 < n) out[base + 1] = e; e += v1;
    if (base + 2 < n) out[base + 2] = e; e += v2;
    if (base + 3 < n) out[base + 3] = e;
}

__global__ __launch_bounds__(256) void scan_bsum(int* __restrict__ bsum, int nb) {
    __shared__ int sh[256];
    int t = threadIdx.x;
    int v = (t < nb) ? bsum[t] : 0;
    sh[t] = v;
    __syncthreads();
    for (int off = 1; off < 256; off <<= 1) {
        int tmp = (t >= off) ? sh[t - off] : 0;
        __syncthreads();
        sh[t] += tmp;
        __syncthreads();
    }
    if (t < nb) bsum[t] = sh[t] - v;  // exclusive
}

// adds block prefix; writes both ofs and cursor (replaces the d2d memcpy)
__global__ __launch_bounds__(256) void scan_add(int* __restrict__ ofs,
                                                int* __restrict__ cursor,
                                                const int* __restrict__ bsum, int n) {
    int i = blockIdx.x * 256 + threadIdx.x;
    if (i < n) {
        int v = ofs[i] + bsum[i >> 10];
        ofs[i] = v;
        cursor[i] = v;
    }
}

// writes per-CSR-position src node and segment id (edge-parallel passes need both)
__global__ __launch_bounds__(256) void scatter_kernel(const int* __restrict__ edge_dst,
                                                      const int* __restrict__ edge_src,
                                                      int* __restrict__ cursor,
                                                      int* __restrict__ pos_src,
                                                      int* __restrict__ pos_seg) {
    int g = blockIdx.x * 256 + threadIdx.x;
    if (g < RE) {
        int r = g / EE;
        int seg = r * NN + edge_dst[g];
        int pos = atomicAdd(&cursor[seg], 1);
        pos_src[pos] = edge_src[g];
        pos_seg[pos] = seg;
    }
}

// ---------------------------------------------------------------------------
// Generic 128-col GEMM, K=128, tile 128 rows x 128 cols, BK=32, 256 threads.
// ACT: 0 = none (+bias)
//      1 = relu(acc+bias)
//      2 = gelu applied to the INPUT during staging; out = beta*(acc+b)+(1-beta)*out_prev
// ---------------------------------------------------------------------------
template<int ACT, typename JT>
__global__ __launch_bounds__(256) void gemm128(const JT jt,
                                               const float* __restrict__ skip_l) {
    __shared__ float lw[32][128];   // W chunk [k][g]
    __shared__ float li[32][132];   // in chunk transposed [k][row]; rows 16B-aligned
    const Job jb = jt.j[blockIdx.y];
    const int tid = threadIdx.x;
    const int row0 = blockIdx.x * 128;
    const int col = (tid & 31) * 4;        // 0..124
    const int rbase = (tid >> 5) * 16;     // 0..112
    float4 acc[16];
    #pragma unroll
    for (int i = 0; i < 16; i++) acc[i] = make_float4(0.f, 0.f, 0.f, 0.f);
    const float4 bb = *(const float4*)(jb.b + col);

    for (int k0 = 0; k0 < 128; k0 += 32) {
        #pragma unroll
        for (int it = 0; it < 4; ++it) {          // stage W 32x128
            int idx = tid + it * 256;
            int kk = idx >> 5;
            int c4 = (idx & 31) * 4;
            *(float4*)&lw[kk][c4] = *(const float4*)(jb.w + (k0 + kk) * 128 + c4);
        }
        #pragma unroll
        for (int p = 0; p < 4; ++p) {             // stage in 128x32 transposed
            int rr = (tid >> 3) + p * 32;
            int kk4 = (tid & 7) * 4;
            int rg = row0 + rr; if (rg >= NN) rg = NN - 1;
            float4 v = *(const float4*)(jb.in + (size_t)rg * 128 + k0 + kk4);
            if (ACT == 2) {   // exact gelu on input element
                v.x = 0.5f * v.x * (1.f + erff(v.x * 0.70710678118654752f));
                v.y = 0.5f * v.y * (1.f + erff(v.y * 0.70710678118654752f));
                v.z = 0.5f * v.z * (1.f + erff(v.z * 0.70710678118654752f));
                v.w = 0.5f * v.w * (1.f + erff(v.w * 0.70710678118654752f));
            }
            li[kk4 + 0][rr] = v.x; li[kk4 + 1][rr] = v.y;
            li[kk4 + 2][rr] = v.z; li[kk4 + 3][rr] = v.w;
        }
        __syncthreads();
        #pragma unroll 4
        for (int kk = 0; kk < 32; kk++) {
            const float4 bv = *(const float4*)&lw[kk][col];
            #pragma unroll
            for (int i4 = 0; i4 < 4; i4++) {
                float4 a4 = *(const float4*)&li[kk][rbase + 4 * i4];
                float4& A0 = acc[4 * i4 + 0];
                float4& A1 = acc[4 * i4 + 1];
                float4& A2 = acc[4 * i4 + 2];
                float4& A3 = acc[4 * i4 + 3];
                A0.x += a4.x * bv.x; A0.y += a4.x * bv.y; A0.z += a4.x * bv.z; A0.w += a4.x * bv.w;
                A1.x += a4.y * bv.x; A1.y += a4.y * bv.y; A1.z += a4.y * bv.z; A1.w += a4.y * bv.w;
                A2.x += a4.z * bv.x; A2.y += a4.z * bv.y; A2.z += a4.z * bv.z; A2.w += a4.z * bv.w;
                A3.x += a4.w * bv.x; A3.y += a4.w * bv.y; A3.z += a4.w * bv.z; A3.w += a4.w * bv.w;
            }
        }
        __syncthreads();
    }
    float beta = 0.f;
    if (ACT == 2) beta = 1.f / (1.f + __expf(-skip_l[blockIdx.y]));
    #pragma unroll
    for (int i = 0; i < 16; i++) {
        int rg = row0 + rbase + i;
        if (rg < NN) {
            float4 o = acc[i];
            o.x += bb.x; o.y += bb.y; o.z += bb.z; o.w += bb.w;
            float* op = jb.out + (size_t)rg * 128 + col;
            if (ACT == 1) {
                o.x = fmaxf(o.x, 0.f); o.y = fmaxf(o.y, 0.f);
                o.z = fmaxf(o.z, 0.f); o.w = fmaxf(o.w, 0.f);
            }
            if (ACT == 2) {
                float4 hv = *(const float4*)op;
                o.x = beta * o.x + (1.f - beta) * hv.x;
                o.y = beta * o.y + (1.f - beta) * hv.y;
                o.z = beta * o.z + (1.f - beta) * hv.z;
                o.w = beta * o.w + (1.f - beta) * hv.w;
            }
            *(float4*)op = o;
        }
    }
}

// ---------------------------------------------------------------------------
// EDGE-PARALLEL score pass: one 128-thread group per CSR position (2/block).
//   qa_d = sum_e q[tdst,n,h,e] * A[r,h,d,e]  (in-register rotation, A is L1-hot)
//   sc   = (sum_d qa_d * k[tsrc,src,h,d]) * p[h]/sqrt(D)  -> alpha[p*4+h] (raw)
// All loads independent across edges -> high MLP, coalesced 512B rows.
// ---------------------------------------------------------------------------
__global__ __launch_bounds__(256) void score_kernel(
        const int* __restrict__ pos_src, const int* __restrict__ pos_seg,
        const int* __restrict__ rel_src, const int* __restrict__ rel_dst,
        const float* __restrict__ qb, const float* __restrict__ kb,
        const float* __restrict__ a_rel_l, const float* __restrict__ p_rel_l,
        float* __restrict__ alpha) {
    int grp = threadIdx.x >> 7;
    int lane = threadIdx.x & 127;
    int p = blockIdx.x * 2 + grp;
    if (p >= RE) return;
    int seg = pos_seg[p];
    int src = pos_src[p];
    int r = seg / NN, n = seg - r * NN;
    int tsrc = rel_src[r], tdst = rel_dst[r];
    int hh = lane >> 5;
    int hsel = threadIdx.x & 32;        // head base lane within the 64-lane wave

    float qv = qb[((size_t)tdst * NN + n) * HH + lane];
    float kv = kb[((size_t)tsrc * NN + src) * HH + lane];
    const float* Arow = a_rel_l + (((size_t)r * NHEADS + hh) * DD + (lane & 31)) * DD;
    float qa = 0.f;
    #pragma unroll
    for (int e = 0; e < 32; e += 4) {
        float4 a4 = *(const float4*)(Arow + e);
        qa += __shfl(qv, hsel + e + 0) * a4.x;
        qa += __shfl(qv, hsel + e + 1) * a4.y;
        qa += __shfl(qv, hsel + e + 2) * a4.z;
        qa += __shfl(qv, hsel + e + 3) * a4.w;
    }
    float prod = qa * kv;
    prod += __shfl_xor(prod, 16);
    prod += __shfl_xor(prod, 8);
    prod += __shfl_xor(prod, 4);
    prod += __shfl_xor(prod, 2);
    prod += __shfl_xor(prod, 1);
    if ((lane & 31) == 0) {
        float sc = prod * p_rel_l[r * NHEADS + hh] * 0.17677669529663687f; // 1/sqrt(32)
        alpha[(size_t)p * NHEADS + hh] = sc;
    }
}

// ---------------------------------------------------------------------------
// Segment stats: one thread per (seg, head). alpha reads are coalesced within
// a segment (consecutive CSR positions); avg c = 2.
// ---------------------------------------------------------------------------
__global__ __launch_bounds__(256) void stats_kernel(
        const int* __restrict__ ofs, const int* __restrict__ cnt,
        const float* __restrict__ alpha,
        float* __restrict__ mbuf, float* __restrict__ dbuf) {
    int idx = blockIdx.x * 256 + threadIdx.x;
    if (idx >= RN * NHEADS) return;
    int seg = idx >> 2, hh = idx & 3;
    int c = cnt[seg];
    if (c == 0) return;
    int base = ofs[seg];
    float m = -INFINITY;
    for (int i = 0; i < c; i++)
        m = fmaxf(m, alpha[(size_t)(base + i) * NHEADS + hh]);
    float den = 0.f;
    for (int i = 0; i < c; i++)
        den += __expf(alpha[(size_t)(base + i) * NHEADS + hh] - m);
    mbuf[idx] = m;
    dbuf[idx] = 1.f / den;
}

// ---------------------------------------------------------------------------
// EDGE-PARALLEL aggregate: o_d = exp(sc-m)*inv * v[tsrc,src,h,d];
// rotate by m_rel; atomicAdd into type-space agg. Independent per edge.
// ---------------------------------------------------------------------------
__global__ __launch_bounds__(256) void aggregate_kernel(
        const int* __restrict__ pos_src, const int* __restrict__ pos_seg,
        const int* __restrict__ rel_src, const int* __restrict__ rel_dst,
        const float* __restrict__ vb, const float* __restrict__ m_rel_l,
        const float* __restrict__ alpha, const float* __restrict__ mbuf,
        const float* __restrict__ dbuf, float* __restrict__ agg) {
    int grp = threadIdx.x >> 7;
    int lane = threadIdx.x & 127;
    int p = blockIdx.x * 2 + grp;
    if (p >= RE) return;
    int seg = pos_seg[p];
    int src = pos_src[p];
    int r = seg / NN, n = seg - r * NN;
    int tsrc = rel_src[r], tdst = rel_dst[r];
    int hh = lane >> 5;
    int hsel = threadIdx.x & 32;

    float sc = alpha[(size_t)p * NHEADS + hh];
    float m = mbuf[(size_t)seg * NHEADS + hh];
    float inv = dbuf[(size_t)seg * NHEADS + hh];
    float a = __expf(sc - m) * inv;
    float o = a * vb[((size_t)tsrc * NN + src) * HH + lane];
    // out_e = sum_d o_d * M[h,d,e]; iteration d reads M[h][d][0..31] coalesced.
    const float* Mcol = m_rel_l + ((size_t)r * NHEADS + hh) * DD * DD + (lane & 31);
    float oe = 0.f;
    #pragma unroll 8
    for (int d = 0; d < 32; d++) {
        oe += __shfl(o, hsel + d) * Mcol[d * 32];
    }
    atomicAdd(&agg[((size_t)tdst * NN + n) * HH + lane], oe);
}

// ---------------------------------------------------------------------------
// Final classifier: out = h[0] @ Wout + bout   (N x 128) @ (128 x 16)
// ---------------------------------------------------------------------------
__global__ __launch_bounds__(256) void final_kernel(const float* __restrict__ h0,
        const float* __restrict__ Wout, const float* __restrict__ bout,
        float* __restrict__ out) {
    __shared__ float w[128 * 16];
    __shared__ float hs[16][132];
    for (int i = threadIdx.x; i < 128 * 16; i += 256) w[i] = Wout[i];
    int row0 = blockIdx.x * 16;
    for (int i = threadIdx.x; i < 16 * 128; i += 256) {
        int rr = i >> 7, kk = i & 127;
        int rg = row0 + rr; if (rg >= NN) rg = NN - 1;
        hs[rr][kk] = h0[(size_t)rg * 128 + kk];
    }
    __syncthreads();
    int rr = threadIdx.x >> 4, colc = threadIdx.x & 15;
    float s = bout[colc];
    #pragma unroll 8
    for (int k = 0; k < 128; k++) s += hs[rr][k] * w[k * 16 + colc];
    int rg = row0 + rr;
    if (rg < NN) out[(size_t)rg * 16 + colc] = s;
}

// ---------------------------------------------------------------------------
extern "C" void kernel_launch(void* const* d_in, const int* in_sizes, int n_in,
                              void* d_out, int out_size, void* d_ws, size_t ws_size,
                              hipStream_t stream) {
    const float* x        = (const float*)d_in[0];
    const int*   edge_src = (const int*)d_in[1];
    const int*   edge_dst = (const int*)d_in[2];
    const int*   rel_src  = (const int*)d_in[3];
    const int*   rel_dst  = (const int*)d_in[4];
    const float* Wenc     = (const float*)d_in[5];
    const float* benc     = (const float*)d_in[6];
    const float* Wk       = (const float*)d_in[7];
    const float* bk       = (const float*)d_in[8];
    const float* Wq       = (const float*)d_in[9];
    const float* bq       = (const float*)d_in[10];
    const float* Wv       = (const float*)d_in[11];
    const float* bv       = (const float*)d_in[12];
    const float* Wa       = (const float*)d_in[13];
    const float* ba       = (const float*)d_in[14];
    const float* skip     = (const float*)d_in[15];
    const float* a_rel    = (const float*)d_in[16];
    const float* m_rel    = (const float*)d_in[17];
    const float* p_rel    = (const float*)d_in[18];
    const float* Wout     = (const float*)d_in[19];
    const float* bout     = (const float*)d_in[20];
    float* out = (float*)d_out;
    float* wsf = (float*)d_ws;

    // workspace layout (floats): 3 type-space tensors + edge buffers + CSR
    const size_t NEED_FLOATS = 3 * TNH + (size_t)RE * NHEADS + 2 * (size_t)RN * NHEADS
                             + 3 * (size_t)RN + 2 * (size_t)RE + 256;
    if (ws_size < NEED_FLOATS * sizeof(float)) {
        zero_kernel<<<313, 256, 0, stream>>>((float4*)out, out_size / 4);
        return;
    }
    float* h    = wsf;
    float* buf1 = h    + TNH;          // q, then v
    float* buf2 = buf1 + TNH;          // k, then agg
    float* alpha = buf2 + TNH;
    float* mbuf  = alpha + (size_t)RE * NHEADS;
    float* dbuf  = mbuf + (size_t)RN * NHEADS;
    int* cnt     = (int*)(dbuf + (size_t)RN * NHEADS);
    int* ofs     = cnt + RN;
    int* cursor  = ofs + RN;
    int* pos_src = cursor + RN;
    int* pos_seg = pos_src + RE;
    int* bsum    = pos_seg + RE;

    const size_t NH = (size_t)NN * HH;
    const int RB = (NN + 127) / 128;   // 157 row blocks

    // ---- CSR build (shared by both layers) ----
    zero_kernel<<<235, 256, 0, stream>>>((float4*)cnt, RN / 4);
    hist_kernel<<<(RE + 255) / 256, 256, 0, stream>>>(edge_dst, cnt);
    int nb = (RN + 1023) / 1024;       // 235
    scan_local<<<nb, 256, 0, stream>>>(cnt, ofs, bsum, RN);
    scan_bsum<<<1, 256, 0, stream>>>(bsum, nb);
    scan_add<<<(RN + 255) / 256, 256, 0, stream>>>(ofs, cursor, bsum, RN);
    scatter_kernel<<<(RE + 255) / 256, 256, 0, stream>>>(edge_dst, edge_src,
                                                         cursor, pos_src, pos_seg);

    // ---- encoder: h = relu(x @ Wenc + benc) ----
    {
        Jobs8 je;
        for (int t = 0; t < 8; t++)
            je.j[t] = { x + t * NH, Wenc + (size_t)t * 128 * 128, benc + t * 128, h + t * NH };
        gemm128<1, Jobs8><<<dim3(RB, 8), 256, 0, stream>>>(je, nullptr);
    }

    // ---- layers ----
    for (int l = 0; l < LL; l++) {
        // q -> buf1, k -> buf2
        Jobs16 jqk;
        for (int t = 0; t < 8; t++) {
            size_t wi = (size_t)(l * TT + t) * 128 * 128;
            size_t bi = (size_t)(l * TT + t) * 128;
            jqk.j[t]     = { h + t * NH, Wq + wi, bq + bi, buf1 + t * NH };
            jqk.j[8 + t] = { h + t * NH, Wk + wi, bk + bi, buf2 + t * NH };
        }
        gemm128<0, Jobs16><<<dim3(RB, 16), 256, 0, stream>>>(jqk, nullptr);

        // edge-parallel scores (reads q,k)
        score_kernel<<<RE / 2, 256, 0, stream>>>(pos_src, pos_seg,
                rel_src, rel_dst, buf1, buf2,
                a_rel + (size_t)l * RR * NHEADS * DD * DD,
                p_rel + (size_t)l * RR * NHEADS, alpha);

        // per-(seg,head) softmax stats
        stats_kernel<<<(RN * NHEADS + 255) / 256, 256, 0, stream>>>(ofs, cnt, alpha, mbuf, dbuf);

        // v -> buf1 (q dead)
        Jobs8 jv;
        for (int t = 0; t < 8; t++) {
            size_t wi = (size_t)(l * TT + t) * 128 * 128;
            size_t bi = (size_t)(l * TT + t) * 128;
            jv.j[t] = { h + t * NH, Wv + wi, bv + bi, buf1 + t * NH };
        }
        gemm128<0, Jobs8><<<dim3(RB, 8), 256, 0, stream>>>(jv, nullptr);

        // agg -> buf2 (k dead): zero then edge-parallel accumulate
        zero_kernel<<<2048, 256, 0, stream>>>((float4*)buf2, (int)(TNH / 4));
        aggregate_kernel<<<RE / 2, 256, 0, stream>>>(pos_src, pos_seg,
                rel_src, rel_dst, buf1,
                m_rel + (size_t)l * RR * NHEADS * DD * DD,
                alpha, mbuf, dbuf, buf2);

        // out-proj + skip blend (reads agg=buf2, blends into h)
        Jobs8 jo;
        for (int t = 0; t < 8; t++) {
            size_t wi = (size_t)(l * TT + t) * 128 * 128;
            size_t bi = (size_t)(l * TT + t) * 128;
            jo.j[t] = { buf2 + t * NH, Wa + wi, ba + bi, h + t * NH };
        }
        gemm128<2, Jobs8><<<dim3(RB, 8), 256, 0, stream>>>(jo, skip + l * TT);
    }

    // ---- classifier ----
    final_kernel<<<NN / 16, 256, 0, stream>>>(h, Wout, bout, out);
}

// Round 10
// 2372.423 us; speedup vs baseline: 1.4192x; 1.4192x over previous
//
#include <hip/hip_runtime.h>
#include <cstdint>
#include <cstddef>

// Problem constants
#define TT 8
#define NN 20000
#define FIN 128
#define HH 128
#define NHEADS 4
#define DD 32
#define RR 12
#define EE 40000
#define LL 2
#define CC 16
#define RN (RR*NN)        // 240000 segments (relation, dst-node)
#define RE (RR*EE)        // 480000 edges total
#define TNH ((size_t)TT*NN*HH)   // 20.48M floats per type-space tensor
#define EPB 32            // edges per score block; EE % EPB == 0 -> single-relation blocks

struct Job { const float* in; const float* w; const float* b; float* out; };
struct Jobs8  { Job j[8]; };
struct Jobs16 { Job j[16]; };

// ---------------------------------------------------------------------------
// zero fill (avoids hipMemsetAsync in the capture path)
// ---------------------------------------------------------------------------
__global__ __launch_bounds__(256) void zero_kernel(float4* __restrict__ p, int n4) {
    int i = blockIdx.x * 256 + threadIdx.x;
    int stride = gridDim.x * 256;
    for (; i < n4; i += stride) p[i] = make_float4(0.f, 0.f, 0.f, 0.f);
}

// ---------------------------------------------------------------------------
// CSR build: histogram -> scan -> scatter (keyed by r*N + edge_dst)
// ---------------------------------------------------------------------------
__global__ __launch_bounds__(256) void hist_kernel(const int* __restrict__ edge_dst,
                                                   int* __restrict__ cnt) {
    int g = blockIdx.x * 256 + threadIdx.x;
    if (g < RE) {
        int r = g / EE;
        atomicAdd(&cnt[r * NN + edge_dst[g]], 1);
    }
}

__global__ __launch_bounds__(256) void scan_local(const int* __restrict__ in,
                                                  int* __restrict__ out,
                                                  int* __restrict__ bsum, int n) {
    __shared__ int sh[256];
    int t = threadIdx.x;
    int base = blockIdx.x * 1024 + t * 4;
    int v0 = (base + 0 < n) ? in[base + 0] : 0;
    int v1 = (base + 1 < n) ? in[base + 1] : 0;
    int v2 = (base + 2 < n) ? in[base + 2] : 0;
    int v3 = (base + 3 < n) ? in[base + 3] : 0;
    int s = v0 + v1 + v2 + v3;
    sh[t] = s;
    __syncthreads();
    for (int off = 1; off < 256; off <<= 1) {
        int tmp = (t >= off) ? sh[t - off] : 0;
        __syncthreads();
        sh[t] += tmp;
        __syncthreads();
    }
    int incl = sh[t];
    int e = incl - s;                 // exclusive prefix of this thread's chunk
    if (t == 255) bsum[blockIdx.x] = incl;
    if (base + 0 < n) out[base + 0] = e; e += v0;
    if (base + 1 < n) out[base + 1] = e; e += v1;
    if (base + 2 < n) out[base + 2] = e; e += v2;
    if (base + 3 < n) out[base + 3] = e;
}

__global__ __launch_bounds__(256) void scan_bsum(int* __restrict__ bsum, int nb) {
    __shared__ int sh[256];
    int t = threadIdx.x;
    int v = (t < nb) ? bsum[t] : 0;
    sh[t] = v;
    __syncthreads();
    for (int off = 1; off < 256; off <<= 1) {
        int tmp = (t >= off) ? sh[t - off] : 0;
        __syncthreads();
        sh[t] += tmp;
        __syncthreads();
    }
    if (t < nb) bsum[t] = sh[t] - v;  // exclusive
}

// adds block prefix; writes both ofs and cursor (replaces the d2d memcpy)
__global__ __launch_bounds__(256) void scan_add(int* __restrict__ ofs,
                                                int* __restrict__ cursor,
                                                const int* __restrict__ bsum, int n) {
    int i = blockIdx.x * 256 + threadIdx.x;
    if (i < n) {
        int v = ofs[i] + bsum[i >> 10];
        ofs[i] = v;
        cursor[i] = v;
    }
}

// writes per-CSR-position src node and segment id (edge-parallel passes need both)
__global__ __launch_bounds__(256) void scatter_kernel(const int* __restrict__ edge_dst,
                                                      const int* __restrict__ edge_src,
                                                      int* __restrict__ cursor,
                                                      int* __restrict__ pos_src,
                                                      int* __restrict__ pos_seg) {
    int g = blockIdx.x * 256 + threadIdx.x;
    if (g < RE) {
        int r = g / EE;
        int seg = r * NN + edge_dst[g];
        int pos = atomicAdd(&cursor[seg], 1);
        pos_src[pos] = edge_src[g];
        pos_seg[pos] = seg;
    }
}

// ---------------------------------------------------------------------------
// Generic 128-col GEMM, K=128, tile 128 rows x 128 cols, BK=32, 256 threads.
// ACT: 0 = none (+bias)
//      1 = relu(acc+bias)
//      2 = gelu applied to the INPUT during staging; out = beta*(acc+b)+(1-beta)*out_prev
// ---------------------------------------------------------------------------
template<int ACT, typename JT>
__global__ __launch_bounds__(256) void gemm128(const JT jt,
                                               const float* __restrict__ skip_l) {
    __shared__ float lw[32][128];   // W chunk [k][g]
    __shared__ float li[32][132];   // in chunk transposed [k][row]; rows 16B-aligned
    const Job jb = jt.j[blockIdx.y];
    const int tid = threadIdx.x;
    const int row0 = blockIdx.x * 128;
    const int col = (tid & 31) * 4;        // 0..124
    const int rbase = (tid >> 5) * 16;     // 0..112
    float4 acc[16];
    #pragma unroll
    for (int i = 0; i < 16; i++) acc[i] = make_float4(0.f, 0.f, 0.f, 0.f);
    const float4 bb = *(const float4*)(jb.b + col);

    for (int k0 = 0; k0 < 128; k0 += 32) {
        #pragma unroll
        for (int it = 0; it < 4; ++it) {          // stage W 32x128
            int idx = tid + it * 256;
            int kk = idx >> 5;
            int c4 = (idx & 31) * 4;
            *(float4*)&lw[kk][c4] = *(const float4*)(jb.w + (k0 + kk) * 128 + c4);
        }
        #pragma unroll
        for (int p = 0; p < 4; ++p) {             // stage in 128x32 transposed
            int rr = (tid >> 3) + p * 32;
            int kk4 = (tid & 7) * 4;
            int rg = row0 + rr; if (rg >= NN) rg = NN - 1;
            float4 v = *(const float4*)(jb.in + (size_t)rg * 128 + k0 + kk4);
            if (ACT == 2) {   // exact gelu on input element
                v.x = 0.5f * v.x * (1.f + erff(v.x * 0.70710678118654752f));
                v.y = 0.5f * v.y * (1.f + erff(v.y * 0.70710678118654752f));
                v.z = 0.5f * v.z * (1.f + erff(v.z * 0.70710678118654752f));
                v.w = 0.5f * v.w * (1.f + erff(v.w * 0.70710678118654752f));
            }
            li[kk4 + 0][rr] = v.x; li[kk4 + 1][rr] = v.y;
            li[kk4 + 2][rr] = v.z; li[kk4 + 3][rr] = v.w;
        }
        __syncthreads();
        #pragma unroll 4
        for (int kk = 0; kk < 32; kk++) {
            const float4 bv = *(const float4*)&lw[kk][col];
            #pragma unroll
            for (int i4 = 0; i4 < 4; i4++) {
                float4 a4 = *(const float4*)&li[kk][rbase + 4 * i4];
                float4& A0 = acc[4 * i4 + 0];
                float4& A1 = acc[4 * i4 + 1];
                float4& A2 = acc[4 * i4 + 2];
                float4& A3 = acc[4 * i4 + 3];
                A0.x += a4.x * bv.x; A0.y += a4.x * bv.y; A0.z += a4.x * bv.z; A0.w += a4.x * bv.w;
                A1.x += a4.y * bv.x; A1.y += a4.y * bv.y; A1.z += a4.y * bv.z; A1.w += a4.y * bv.w;
                A2.x += a4.z * bv.x; A2.y += a4.z * bv.y; A2.z += a4.z * bv.z; A2.w += a4.z * bv.w;
                A3.x += a4.w * bv.x; A3.y += a4.w * bv.y; A3.z += a4.w * bv.z; A3.w += a4.w * bv.w;
            }
        }
        __syncthreads();
    }
    float beta = 0.f;
    if (ACT == 2) beta = 1.f / (1.f + __expf(-skip_l[blockIdx.y]));
    #pragma unroll
    for (int i = 0; i < 16; i++) {
        int rg = row0 + rbase + i;
        if (rg < NN) {
            float4 o = acc[i];
            o.x += bb.x; o.y += bb.y; o.z += bb.z; o.w += bb.w;
            float* op = jb.out + (size_t)rg * 128 + col;
            if (ACT == 1) {
                o.x = fmaxf(o.x, 0.f); o.y = fmaxf(o.y, 0.f);
                o.z = fmaxf(o.z, 0.f); o.w = fmaxf(o.w, 0.f);
            }
            if (ACT == 2) {
                float4 hv = *(const float4*)op;
                o.x = beta * o.x + (1.f - beta) * hv.x;
                o.y = beta * o.y + (1.f - beta) * hv.y;
                o.z = beta * o.z + (1.f - beta) * hv.z;
                o.w = beta * o.w + (1.f - beta) * hv.w;
            }
            *(float4*)op = o;
        }
    }
}

// ---------------------------------------------------------------------------
// EDGE-PARALLEL score pass, 32 edges per block (all same relation since
// EE % EPB == 0 and CSR positions are relation-contiguous).
// A[r] staged in LDS with +1-padded rows: As[h][d][33] -> read bank (d+e)%32,
// conflict-free (2 lanes/bank across a wave = free). qa rotation becomes
// 32x {ds_read_b32 + shfl + fma} per edge instead of 8 loads x 64 cachelines.
// 1-edge software prefetch on the q/k row gathers.
// ---------------------------------------------------------------------------
__global__ __launch_bounds__(256) void score_kernel(
        const int* __restrict__ pos_src, const int* __restrict__ pos_seg,
        const int* __restrict__ rel_src, const int* __restrict__ rel_dst,
        const float* __restrict__ qb, const float* __restrict__ kb,
        const float* __restrict__ a_rel_l, const float* __restrict__ p_rel_l,
        float* __restrict__ alpha) {
    __shared__ float As[NHEADS * DD * 33];   // 16.9 KB
    int tid = threadIdx.x;
    int base = blockIdx.x * EPB;
    int r = pos_seg[base] / NN;              // uniform across the block
    const float* Ag = a_rel_l + (size_t)r * NHEADS * DD * DD;
    for (int idx = tid; idx < NHEADS * DD * DD; idx += 256)
        As[(idx >> 5) * 33 + (idx & 31)] = Ag[idx];
    __syncthreads();

    int egrp = tid >> 7;            // 0..1 (128-thread group per edge stream)
    int lane = tid & 127;
    int hh = lane >> 5;
    int d = lane & 31;
    int hsel = tid & 32;            // head base within the 64-lane wave
    int tsrc = rel_src[r], tdst = rel_dst[r];
    float pscale = p_rel_l[r * NHEADS + hh] * 0.17677669529663687f; // 1/sqrt(32)
    const float* Ah = &As[(hh * 32 + d) * 33];

    int p0 = base + egrp * (EPB / 2);
    int seg = pos_seg[p0], src = pos_src[p0];
    float qv = qb[((size_t)tdst * NN + (seg - r * NN)) * HH + lane];
    float kv = kb[((size_t)tsrc * NN + src) * HH + lane];
    #pragma unroll 4
    for (int i = 0; i < EPB / 2; i++) {
        // prefetch next edge (wraps at the tail; redundant load, no branch)
        int pn = p0 + ((i + 1) & (EPB / 2 - 1));
        int seg2 = pos_seg[pn];
        int src2 = pos_src[pn];
        float qv2 = qb[((size_t)tdst * NN + (seg2 - r * NN)) * HH + lane];
        float kv2 = kb[((size_t)tsrc * NN + src2) * HH + lane];

        float qa = 0.f;
        #pragma unroll
        for (int e = 0; e < 32; e++)
            qa += __shfl(qv, hsel + e) * Ah[e];
        float prod = qa * kv;
        prod += __shfl_xor(prod, 16);
        prod += __shfl_xor(prod, 8);
        prod += __shfl_xor(prod, 4);
        prod += __shfl_xor(prod, 2);
        prod += __shfl_xor(prod, 1);
        if (d == 0) alpha[(size_t)(p0 + i) * NHEADS + hh] = prod * pscale;

        seg = seg2; src = src2; qv = qv2; kv = kv2;
    }
}

// ---------------------------------------------------------------------------
// Segment stats: one thread per (seg, head). alpha reads are coalesced within
// a segment (consecutive CSR positions); avg c = 2.
// ---------------------------------------------------------------------------
__global__ __launch_bounds__(256) void stats_kernel(
        const int* __restrict__ ofs, const int* __restrict__ cnt,
        const float* __restrict__ alpha,
        float* __restrict__ mbuf, float* __restrict__ dbuf) {
    int idx = blockIdx.x * 256 + threadIdx.x;
    if (idx >= RN * NHEADS) return;
    int seg = idx >> 2, hh = idx & 3;
    int c = cnt[seg];
    if (c == 0) return;
    int base = ofs[seg];
    float m = -INFINITY;
    for (int i = 0; i < c; i++)
        m = fmaxf(m, alpha[(size_t)(base + i) * NHEADS + hh]);
    float den = 0.f;
    for (int i = 0; i < c; i++)
        den += __expf(alpha[(size_t)(base + i) * NHEADS + hh] - m);
    mbuf[idx] = m;
    dbuf[idx] = 1.f / den;
}

// ---------------------------------------------------------------------------
// EDGE-PARALLEL aggregate: o_d = exp(sc-m)*inv * v[tsrc,src,h,d];
// rotate by m_rel; atomicAdd into type-space agg. Independent per edge.
// (M column reads are lane-coalesced and L1-resident; unchanged this round.)
// ---------------------------------------------------------------------------
__global__ __launch_bounds__(256) void aggregate_kernel(
        const int* __restrict__ pos_src, const int* __restrict__ pos_seg,
        const int* __restrict__ rel_src, const int* __restrict__ rel_dst,
        const float* __restrict__ vb, const float* __restrict__ m_rel_l,
        const float* __restrict__ alpha, const float* __restrict__ mbuf,
        const float* __restrict__ dbuf, float* __restrict__ agg) {
    int grp = threadIdx.x >> 7;
    int lane = threadIdx.x & 127;
    int p = blockIdx.x * 2 + grp;
    if (p >= RE) return;
    int seg = pos_seg[p];
    int src = pos_src[p];
    int r = seg / NN, n = seg - r * NN;
    int tsrc = rel_src[r], tdst = rel_dst[r];
    int hh = lane >> 5;
    int hsel = threadIdx.x & 32;

    float sc = alpha[(size_t)p * NHEADS + hh];
    float m = mbuf[(size_t)seg * NHEADS + hh];
    float inv = dbuf[(size_t)seg * NHEADS + hh];
    float a = __expf(sc - m) * inv;
    float o = a * vb[((size_t)tsrc * NN + src) * HH + lane];
    // out_e = sum_d o_d * M[h,d,e]; iteration d reads M[h][d][0..31] coalesced.
    const float* Mcol = m_rel_l + ((size_t)r * NHEADS + hh) * DD * DD + (lane & 31);
    float oe = 0.f;
    #pragma unroll 8
    for (int d = 0; d < 32; d++) {
        oe += __shfl(o, hsel + d) * Mcol[d * 32];
    }
    atomicAdd(&agg[((size_t)tdst * NN + n) * HH + lane], oe);
}

// ---------------------------------------------------------------------------
// Final classifier: out = h[0] @ Wout + bout   (N x 128) @ (128 x 16)
// ---------------------------------------------------------------------------
__global__ __launch_bounds__(256) void final_kernel(const float* __restrict__ h0,
        const float* __restrict__ Wout, const float* __restrict__ bout,
        float* __restrict__ out) {
    __shared__ float w[128 * 16];
    __shared__ float hs[16][132];
    for (int i = threadIdx.x; i < 128 * 16; i += 256) w[i] = Wout[i];
    int row0 = blockIdx.x * 16;
    for (int i = threadIdx.x; i < 16 * 128; i += 256) {
        int rr = i >> 7, kk = i & 127;
        int rg = row0 + rr; if (rg >= NN) rg = NN - 1;
        hs[rr][kk] = h0[(size_t)rg * 128 + kk];
    }
    __syncthreads();
    int rr = threadIdx.x >> 4, colc = threadIdx.x & 15;
    float s = bout[colc];
    #pragma unroll 8
    for (int k = 0; k < 128; k++) s += hs[rr][k] * w[k * 16 + colc];
    int rg = row0 + rr;
    if (rg < NN) out[(size_t)rg * 16 + colc] = s;
}

// ---------------------------------------------------------------------------
extern "C" void kernel_launch(void* const* d_in, const int* in_sizes, int n_in,
                              void* d_out, int out_size, void* d_ws, size_t ws_size,
                              hipStream_t stream) {
    const float* x        = (const float*)d_in[0];
    const int*   edge_src = (const int*)d_in[1];
    const int*   edge_dst = (const int*)d_in[2];
    const int*   rel_src  = (const int*)d_in[3];
    const int*   rel_dst  = (const int*)d_in[4];
    const float* Wenc     = (const float*)d_in[5];
    const float* benc     = (const float*)d_in[6];
    const float* Wk       = (const float*)d_in[7];
    const float* bk       = (const float*)d_in[8];
    const float* Wq       = (const float*)d_in[9];
    const float* bq       = (const float*)d_in[10];
    const float* Wv       = (const float*)d_in[11];
    const float* bv       = (const float*)d_in[12];
    const float* Wa       = (const float*)d_in[13];
    const float* ba       = (const float*)d_in[14];
    const float* skip     = (const float*)d_in[15];
    const float* a_rel    = (const float*)d_in[16];
    const float* m_rel    = (const float*)d_in[17];
    const float* p_rel    = (const float*)d_in[18];
    const float* Wout     = (const float*)d_in[19];
    const float* bout     = (const float*)d_in[20];
    float* out = (float*)d_out;
    float* wsf = (float*)d_ws;

    // workspace layout (floats): 3 type-space tensors + edge buffers + CSR
    const size_t NEED_FLOATS = 3 * TNH + (size_t)RE * NHEADS + 2 * (size_t)RN * NHEADS
                             + 3 * (size_t)RN + 2 * (size_t)RE + 256;
    if (ws_size < NEED_FLOATS * sizeof(float)) {
        zero_kernel<<<313, 256, 0, stream>>>((float4*)out, out_size / 4);
        return;
    }
    float* h    = wsf;
    float* buf1 = h    + TNH;          // q, then v
    float* buf2 = buf1 + TNH;          // k, then agg
    float* alpha = buf2 + TNH;
    float* mbuf  = alpha + (size_t)RE * NHEADS;
    float* dbuf  = mbuf + (size_t)RN * NHEADS;
    int* cnt     = (int*)(dbuf + (size_t)RN * NHEADS);
    int* ofs     = cnt + RN;
    int* cursor  = ofs + RN;
    int* pos_src = cursor + RN;
    int* pos_seg = pos_src + RE;
    int* bsum    = pos_seg + RE;

    const size_t NH = (size_t)NN * HH;
    const int RB = (NN + 127) / 128;   // 157 row blocks

    // ---- CSR build (shared by both layers) ----
    zero_kernel<<<235, 256, 0, stream>>>((float4*)cnt, RN / 4);
    hist_kernel<<<(RE + 255) / 256, 256, 0, stream>>>(edge_dst, cnt);
    int nb = (RN + 1023) / 1024;       // 235
    scan_local<<<nb, 256, 0, stream>>>(cnt, ofs, bsum, RN);
    scan_bsum<<<1, 256, 0, stream>>>(bsum, nb);
    scan_add<<<(RN + 255) / 256, 256, 0, stream>>>(ofs, cursor, bsum, RN);
    scatter_kernel<<<(RE + 255) / 256, 256, 0, stream>>>(edge_dst, edge_src,
                                                         cursor, pos_src, pos_seg);

    // ---- encoder: h = relu(x @ Wenc + benc) ----
    {
        Jobs8 je;
        for (int t = 0; t < 8; t++)
            je.j[t] = { x + t * NH, Wenc + (size_t)t * 128 * 128, benc + t * 128, h + t * NH };
        gemm128<1, Jobs8><<<dim3(RB, 8), 256, 0, stream>>>(je, nullptr);
    }

    // ---- layers ----
    for (int l = 0; l < LL; l++) {
        // q -> buf1, k -> buf2
        Jobs16 jqk;
        for (int t = 0; t < 8; t++) {
            size_t wi = (size_t)(l * TT + t) * 128 * 128;
            size_t bi = (size_t)(l * TT + t) * 128;
            jqk.j[t]     = { h + t * NH, Wq + wi, bq + bi, buf1 + t * NH };
            jqk.j[8 + t] = { h + t * NH, Wk + wi, bk + bi, buf2 + t * NH };
        }
        gemm128<0, Jobs16><<<dim3(RB, 16), 256, 0, stream>>>(jqk, nullptr);

        // edge-parallel scores, 32 edges per block, LDS-staged A (reads q,k)
        score_kernel<<<RE / EPB, 256, 0, stream>>>(pos_src, pos_seg,
                rel_src, rel_dst, buf1, buf2,
                a_rel + (size_t)l * RR * NHEADS * DD * DD,
                p_rel + (size_t)l * RR * NHEADS, alpha);

        // per-(seg,head) softmax stats
        stats_kernel<<<(RN * NHEADS + 255) / 256, 256, 0, stream>>>(ofs, cnt, alpha, mbuf, dbuf);

        // v -> buf1 (q dead)
        Jobs8 jv;
        for (int t = 0; t < 8; t++) {
            size_t wi = (size_t)(l * TT + t) * 128 * 128;
            size_t bi = (size_t)(l * TT + t) * 128;
            jv.j[t] = { h + t * NH, Wv + wi, bv + bi, buf1 + t * NH };
        }
        gemm128<0, Jobs8><<<dim3(RB, 8), 256, 0, stream>>>(jv, nullptr);

        // agg -> buf2 (k dead): zero then edge-parallel accumulate
        zero_kernel<<<2048, 256, 0, stream>>>((float4*)buf2, (int)(TNH / 4));
        aggregate_kernel<<<RE / 2, 256, 0, stream>>>(pos_src, pos_seg,
                rel_src, rel_dst, buf1,
                m_rel + (size_t)l * RR * NHEADS * DD * DD,
                alpha, mbuf, dbuf, buf2);

        // out-proj + skip blend (reads agg=buf2, blends into h)
        Jobs8 jo;
        for (int t = 0; t < 8; t++) {
            size_t wi = (size_t)(l * TT + t) * 128 * 128;
            size_t bi = (size_t)(l * TT + t) * 128;
            jo.j[t] = { buf2 + t * NH, Wa + wi, ba + bi, h + t * NH };
        }
        gemm128<2, Jobs8><<<dim3(RB, 8), 256, 0, stream>>>(jo, skip + l * TT);
    }

    // ---- classifier ----
    final_kernel<<<NN / 16, 256, 0, stream>>>(h, Wout, bout, out);
}

// Round 11
// 2074.299 us; speedup vs baseline: 1.6232x; 1.1437x over previous
//
#include <hip/hip_runtime.h>
#include <cstdint>
#include <cstddef>

// Problem constants
#define TT 8
#define NN 20000
#define FIN 128
#define HH 128
#define NHEADS 4
#define DD 32
#define RR 12
#define EE 40000
#define LL 2
#define CC 16
#define RN (RR*NN)        // 240000 segments (relation, dst-node)
#define RE (RR*EE)        // 480000 edges total
#define TNH ((size_t)TT*NN*HH)   // 20.48M floats per type-space tensor
#define NH_ ((size_t)NN*HH)

struct Job { const float* in; const float* w; const float* b; float* out; };
struct Jobs8  { Job j[8]; };

// ---------------------------------------------------------------------------
// zero fill (avoids hipMemsetAsync in the capture path)
// ---------------------------------------------------------------------------
__global__ __launch_bounds__(256) void zero_kernel(float4* __restrict__ p, int n4) {
    int i = blockIdx.x * 256 + threadIdx.x;
    int stride = gridDim.x * 256;
    for (; i < n4; i += stride) p[i] = make_float4(0.f, 0.f, 0.f, 0.f);
}

// ---------------------------------------------------------------------------
// CSR build: histogram -> scan -> scatter (keyed by r*N + edge_dst)
// ---------------------------------------------------------------------------
__global__ __launch_bounds__(256) void hist_kernel(const int* __restrict__ edge_dst,
                                                   int* __restrict__ cnt) {
    int g = blockIdx.x * 256 + threadIdx.x;
    if (g < RE) {
        int r = g / EE;
        atomicAdd(&cnt[r * NN + edge_dst[g]], 1);
    }
}

__global__ __launch_bounds__(256) void scan_local(const int* __restrict__ in,
                                                  int* __restrict__ out,
                                                  int* __restrict__ bsum, int n) {
    __shared__ int sh[256];
    int t = threadIdx.x;
    int base = blockIdx.x * 1024 + t * 4;
    int v0 = (base + 0 < n) ? in[base + 0] : 0;
    int v1 = (base + 1 < n) ? in[base + 1] : 0;
    int v2 = (base + 2 < n) ? in[base + 2] : 0;
    int v3 = (base + 3 < n) ? in[base + 3] : 0;
    int s = v0 + v1 + v2 + v3;
    sh[t] = s;
    __syncthreads();
    for (int off = 1; off < 256; off <<= 1) {
        int tmp = (t >= off) ? sh[t - off] : 0;
        __syncthreads();
        sh[t] += tmp;
        __syncthreads();
    }
    int incl = sh[t];
    int e = incl - s;
    if (t == 255) bsum[blockIdx.x] = incl;
    if (base + 0 < n) out[base + 0] = e; e += v0;
    if (base + 1 < n) out[base + 1] = e; e += v1;
    if (base + 2 < n) out[base + 2] = e; e += v2;
    if (base + 3 < n) out[base + 3] = e;
}

__global__ __launch_bounds__(256) void scan_bsum(int* __restrict__ bsum, int nb) {
    __shared__ int sh[256];
    int t = threadIdx.x;
    int v = (t < nb) ? bsum[t] : 0;
    sh[t] = v;
    __syncthreads();
    for (int off = 1; off < 256; off <<= 1) {
        int tmp = (t >= off) ? sh[t - off] : 0;
        __syncthreads();
        sh[t] += tmp;
        __syncthreads();
    }
    if (t < nb) bsum[t] = sh[t] - v;  // exclusive
}

__global__ __launch_bounds__(256) void scan_add(int* __restrict__ ofs,
                                                int* __restrict__ cursor,
                                                const int* __restrict__ bsum, int n) {
    int i = blockIdx.x * 256 + threadIdx.x;
    if (i < n) {
        int v = ofs[i] + bsum[i >> 10];
        ofs[i] = v;
        cursor[i] = v;
    }
}

__global__ __launch_bounds__(256) void scatter_kernel(const int* __restrict__ edge_dst,
                                                      const int* __restrict__ edge_src,
                                                      int* __restrict__ cursor,
                                                      int* __restrict__ pos_src,
                                                      int* __restrict__ pos_seg) {
    int g = blockIdx.x * 256 + threadIdx.x;
    if (g < RE) {
        int r = g / EE;
        int seg = r * NN + edge_dst[g];
        int pos = atomicAdd(&cursor[seg], 1);
        pos_src[pos] = edge_src[g];
        pos_seg[pos] = seg;
    }
}

// ---------------------------------------------------------------------------
// Folded per-relation weights (kills the in-kernel shfl rotations):
//   W_qa[r][f][h*32+d] = sum_e Wq[tdst(r)][f][h*32+e] * A[r][h][d][e]
//   W_va[r][f][h*32+e] = sum_d Wv[tsrc(r)][f][h*32+d] * M[r][h][d][e]
// plus the matching folded biases. One block per relation.
// LDS layouts padded (+1) so compute reads are bank-conflict-free.
// ---------------------------------------------------------------------------
__global__ __launch_bounds__(256) void weff_kernel(
        const int* __restrict__ rel_src, const int* __restrict__ rel_dst,
        const float* __restrict__ Wq, const float* __restrict__ bq,
        const float* __restrict__ Wv, const float* __restrict__ bv,
        const float* __restrict__ a_rel_l, const float* __restrict__ m_rel_l,
        int l,
        float* __restrict__ Wqa, float* __restrict__ bqa,
        float* __restrict__ Wva, float* __restrict__ bva) {
    __shared__ float AsT[NHEADS * DD * 33];  // [h][e][d] (transposed A)
    __shared__ float Ms [NHEADS * DD * 33];  // [h][d][e]
    int r = blockIdx.x;
    int tid = threadIdx.x;
    int tdst = rel_dst[r], tsrc = rel_src[r];
    const float* A = a_rel_l + (size_t)r * NHEADS * DD * DD;
    const float* M = m_rel_l + (size_t)r * NHEADS * DD * DD;
    for (int idx = tid; idx < NHEADS * DD * DD; idx += 256) {
        int h_ = idx >> 10, rem = idx & 1023, d = rem >> 5, e = rem & 31;
        AsT[(h_ * 32 + e) * 33 + d] = A[idx];
        Ms [(h_ * 32 + d) * 33 + e] = M[idx];
    }
    __syncthreads();
    int col = tid & 127, half = tid >> 7;
    int hh = col >> 5, x = col & 31;
    const float* Wqb = Wq + (size_t)(l * TT + tdst) * HH * HH;
    const float* Wvb = Wv + (size_t)(l * TT + tsrc) * HH * HH;
    for (int f0 = 0; f0 < HH; f0 += 2) {
        int f = f0 + half;
        float sq = 0.f, sv = 0.f;
        #pragma unroll
        for (int i = 0; i < 32; i++) {
            sq += Wqb[f * HH + hh * 32 + i] * AsT[(hh * 32 + i) * 33 + x]; // i=e, x=d
            sv += Wvb[f * HH + hh * 32 + i] * Ms [(hh * 32 + i) * 33 + x]; // i=d, x=e
        }
        Wqa[((size_t)r * HH + f) * HH + col] = sq;
        Wva[((size_t)r * HH + f) * HH + col] = sv;
    }
    if (half == 0) {
        const float* bqb = bq + (size_t)(l * TT + tdst) * HH;
        float s = 0.f;
        #pragma unroll
        for (int e = 0; e < 32; e++) s += bqb[hh * 32 + e] * AsT[(hh * 32 + e) * 33 + x];
        bqa[r * HH + col] = s;
    } else {
        const float* bvb = bv + (size_t)(l * TT + tsrc) * HH;
        float s = 0.f;
        #pragma unroll
        for (int d = 0; d < 32; d++) s += bvb[hh * 32 + d] * Ms[(hh * 32 + d) * 33 + x];
        bva[r * HH + col] = s;
    }
}

// ---------------------------------------------------------------------------
// Generic 128-col GEMM, K=128, tile 128x128, BK=32, 256 threads.
// ACT: 0 = none(+bias), 1 = relu(+bias), 2 = gelu on input; skip-blend output
// ---------------------------------------------------------------------------
template<int ACT, typename JT>
__global__ __launch_bounds__(256) void gemm128(const JT jt,
                                               const float* __restrict__ skip_l) {
    __shared__ float lw[32][128];
    __shared__ float li[32][132];
    const Job jb = jt.j[blockIdx.y];
    const int tid = threadIdx.x;
    const int row0 = blockIdx.x * 128;
    const int col = (tid & 31) * 4;
    const int rbase = (tid >> 5) * 16;
    float4 acc[16];
    #pragma unroll
    for (int i = 0; i < 16; i++) acc[i] = make_float4(0.f, 0.f, 0.f, 0.f);
    const float4 bb = *(const float4*)(jb.b + col);

    for (int k0 = 0; k0 < 128; k0 += 32) {
        #pragma unroll
        for (int it = 0; it < 4; ++it) {
            int idx = tid + it * 256;
            int kk = idx >> 5;
            int c4 = (idx & 31) * 4;
            *(float4*)&lw[kk][c4] = *(const float4*)(jb.w + (k0 + kk) * 128 + c4);
        }
        #pragma unroll
        for (int p = 0; p < 4; ++p) {
            int rr = (tid >> 3) + p * 32;
            int kk4 = (tid & 7) * 4;
            int rg = row0 + rr; if (rg >= NN) rg = NN - 1;
            float4 v = *(const float4*)(jb.in + (size_t)rg * 128 + k0 + kk4);
            if (ACT == 2) {
                v.x = 0.5f * v.x * (1.f + erff(v.x * 0.70710678118654752f));
                v.y = 0.5f * v.y * (1.f + erff(v.y * 0.70710678118654752f));
                v.z = 0.5f * v.z * (1.f + erff(v.z * 0.70710678118654752f));
                v.w = 0.5f * v.w * (1.f + erff(v.w * 0.70710678118654752f));
            }
            li[kk4 + 0][rr] = v.x; li[kk4 + 1][rr] = v.y;
            li[kk4 + 2][rr] = v.z; li[kk4 + 3][rr] = v.w;
        }
        __syncthreads();
        #pragma unroll 4
        for (int kk = 0; kk < 32; kk++) {
            const float4 bv = *(const float4*)&lw[kk][col];
            #pragma unroll
            for (int i4 = 0; i4 < 4; i4++) {
                float4 a4 = *(const float4*)&li[kk][rbase + 4 * i4];
                float4& A0 = acc[4 * i4 + 0];
                float4& A1 = acc[4 * i4 + 1];
                float4& A2 = acc[4 * i4 + 2];
                float4& A3 = acc[4 * i4 + 3];
                A0.x += a4.x * bv.x; A0.y += a4.x * bv.y; A0.z += a4.x * bv.z; A0.w += a4.x * bv.w;
                A1.x += a4.y * bv.x; A1.y += a4.y * bv.y; A1.z += a4.y * bv.z; A1.w += a4.y * bv.w;
                A2.x += a4.z * bv.x; A2.y += a4.z * bv.y; A2.z += a4.z * bv.z; A2.w += a4.z * bv.w;
                A3.x += a4.w * bv.x; A3.y += a4.w * bv.y; A3.z += a4.w * bv.z; A3.w += a4.w * bv.w;
            }
        }
        __syncthreads();
    }
    float beta = 0.f;
    if (ACT == 2) beta = 1.f / (1.f + __expf(-skip_l[blockIdx.y]));
    #pragma unroll
    for (int i = 0; i < 16; i++) {
        int rg = row0 + rbase + i;
        if (rg < NN) {
            float4 o = acc[i];
            o.x += bb.x; o.y += bb.y; o.z += bb.z; o.w += bb.w;
            float* op = jb.out + (size_t)rg * 128 + col;
            if (ACT == 1) {
                o.x = fmaxf(o.x, 0.f); o.y = fmaxf(o.y, 0.f);
                o.z = fmaxf(o.z, 0.f); o.w = fmaxf(o.w, 0.f);
            }
            if (ACT == 2) {
                float4 hv = *(const float4*)op;
                o.x = beta * o.x + (1.f - beta) * hv.x;
                o.y = beta * o.y + (1.f - beta) * hv.y;
                o.z = beta * o.z + (1.f - beta) * hv.z;
                o.w = beta * o.w + (1.f - beta) * hv.w;
            }
            *(float4*)op = o;
        }
    }
}

// ---------------------------------------------------------------------------
// Per-relation GEMM: in = h[type(r)], w = folded W[r], out = chunk-local slab.
// Relation types are device-resident -> resolved in-kernel.
// ---------------------------------------------------------------------------
__global__ __launch_bounds__(256) void gemm128_rel(
        const float* __restrict__ hbase, const int* __restrict__ rtype, int r0,
        const float* __restrict__ Wbase, const float* __restrict__ Bbase,
        float* __restrict__ outbase) {
    __shared__ float lw[32][128];
    __shared__ float li[32][132];
    const int r = r0 + blockIdx.y;
    const float* in = hbase + (size_t)rtype[r] * NH_;
    const float* w  = Wbase + (size_t)r * HH * HH;
    const float* b  = Bbase + (size_t)r * HH;
    float* outp = outbase + (size_t)blockIdx.y * NH_;
    const int tid = threadIdx.x;
    const int row0 = blockIdx.x * 128;
    const int col = (tid & 31) * 4;
    const int rbase = (tid >> 5) * 16;
    float4 acc[16];
    #pragma unroll
    for (int i = 0; i < 16; i++) acc[i] = make_float4(0.f, 0.f, 0.f, 0.f);
    const float4 bb = *(const float4*)(b + col);

    for (int k0 = 0; k0 < 128; k0 += 32) {
        #pragma unroll
        for (int it = 0; it < 4; ++it) {
            int idx = tid + it * 256;
            int kk = idx >> 5;
            int c4 = (idx & 31) * 4;
            *(float4*)&lw[kk][c4] = *(const float4*)(w + (k0 + kk) * 128 + c4);
        }
        #pragma unroll
        for (int p = 0; p < 4; ++p) {
            int rr = (tid >> 3) + p * 32;
            int kk4 = (tid & 7) * 4;
            int rg = row0 + rr; if (rg >= NN) rg = NN - 1;
            float4 v = *(const float4*)(in + (size_t)rg * 128 + k0 + kk4);
            li[kk4 + 0][rr] = v.x; li[kk4 + 1][rr] = v.y;
            li[kk4 + 2][rr] = v.z; li[kk4 + 3][rr] = v.w;
        }
        __syncthreads();
        #pragma unroll 4
        for (int kk = 0; kk < 32; kk++) {
            const float4 bv = *(const float4*)&lw[kk][col];
            #pragma unroll
            for (int i4 = 0; i4 < 4; i4++) {
                float4 a4 = *(const float4*)&li[kk][rbase + 4 * i4];
                float4& A0 = acc[4 * i4 + 0];
                float4& A1 = acc[4 * i4 + 1];
                float4& A2 = acc[4 * i4 + 2];
                float4& A3 = acc[4 * i4 + 3];
                A0.x += a4.x * bv.x; A0.y += a4.x * bv.y; A0.z += a4.x * bv.z; A0.w += a4.x * bv.w;
                A1.x += a4.y * bv.x; A1.y += a4.y * bv.y; A1.z += a4.y * bv.z; A1.w += a4.y * bv.w;
                A2.x += a4.z * bv.x; A2.y += a4.z * bv.y; A2.z += a4.z * bv.z; A2.w += a4.z * bv.w;
                A3.x += a4.w * bv.x; A3.y += a4.w * bv.y; A3.z += a4.w * bv.z; A3.w += a4.w * bv.w;
            }
        }
        __syncthreads();
    }
    #pragma unroll
    for (int i = 0; i < 16; i++) {
        int rg = row0 + rbase + i;
        if (rg < NN) {
            float4 o = acc[i];
            o.x += bb.x; o.y += bb.y; o.z += bb.z; o.w += bb.w;
            *(float4*)(outp + (size_t)rg * 128 + col) = o;
        }
    }
}

// ---------------------------------------------------------------------------
// Score: per edge, sc[h] = (qa[r,n_dst] . k[tsrc,src]) per 32-lane head group.
// Pure gather + 5 shfl_xor; no rotation, no LDS.
// ---------------------------------------------------------------------------
__global__ __launch_bounds__(256) void score_kernel(
        const int* __restrict__ pos_src, const int* __restrict__ pos_seg,
        const int* __restrict__ rel_src, int p0, int r0,
        const float* __restrict__ qa, const float* __restrict__ kb,
        const float* __restrict__ p_rel_l, float* __restrict__ alpha) {
    int grp = threadIdx.x >> 7;
    int lane = threadIdx.x & 127;
    int p = p0 + blockIdx.x * 2 + grp;
    int seg = pos_seg[p], src = pos_src[p];
    int r = seg / NN, n = seg - r * NN;
    int tsrc = rel_src[r];
    int hh = lane >> 5;
    float qv = qa[((size_t)(r - r0) * NN + n) * HH + lane];
    float kv = kb[((size_t)tsrc * NN + src) * HH + lane];
    float prod = qv * kv;
    prod += __shfl_xor(prod, 16);
    prod += __shfl_xor(prod, 8);
    prod += __shfl_xor(prod, 4);
    prod += __shfl_xor(prod, 2);
    prod += __shfl_xor(prod, 1);
    if ((lane & 31) == 0)
        alpha[(size_t)p * NHEADS + hh] = prod * p_rel_l[r * NHEADS + hh]
                                        * 0.17677669529663687f; // 1/sqrt(32)
}

// ---------------------------------------------------------------------------
// Segment stats: one thread per (seg, head); coalesced alpha reads, avg c=2.
// ---------------------------------------------------------------------------
__global__ __launch_bounds__(256) void stats_kernel(
        const int* __restrict__ ofs, const int* __restrict__ cnt,
        const float* __restrict__ alpha,
        float* __restrict__ mbuf, float* __restrict__ dbuf) {
    int idx = blockIdx.x * 256 + threadIdx.x;
    if (idx >= RN * NHEADS) return;
    int seg = idx >> 2, hh = idx & 3;
    int c = cnt[seg];
    if (c == 0) return;
    int base = ofs[seg];
    float m = -INFINITY;
    for (int i = 0; i < c; i++)
        m = fmaxf(m, alpha[(size_t)(base + i) * NHEADS + hh]);
    float den = 0.f;
    for (int i = 0; i < c; i++)
        den += __expf(alpha[(size_t)(base + i) * NHEADS + hh] - m);
    mbuf[idx] = m;
    dbuf[idx] = 1.f / den;
}

// ---------------------------------------------------------------------------
// Aggregate: per edge, agg[tdst,n_dst] += softmax_weight * va[r, src].
// Pure gather + atomicAdd; no rotation, no shfl.
// ---------------------------------------------------------------------------
__global__ __launch_bounds__(256) void aggregate_kernel(
        const int* __restrict__ pos_src, const int* __restrict__ pos_seg,
        const int* __restrict__ rel_dst, int p0, int r0,
        const float* __restrict__ va, const float* __restrict__ alpha,
        const float* __restrict__ mbuf, const float* __restrict__ dbuf,
        float* __restrict__ agg) {
    int grp = threadIdx.x >> 7;
    int lane = threadIdx.x & 127;
    int p = p0 + blockIdx.x * 2 + grp;
    int seg = pos_seg[p], src = pos_src[p];
    int r = seg / NN, n = seg - r * NN;
    int tdst = rel_dst[r];
    int hh = lane >> 5;
    float sc = alpha[(size_t)p * NHEADS + hh];
    float a = __expf(sc - mbuf[(size_t)seg * NHEADS + hh]) * dbuf[(size_t)seg * NHEADS + hh];
    float vv = va[((size_t)(r - r0) * NN + src) * HH + lane];
    atomicAdd(&agg[((size_t)tdst * NN + n) * HH + lane], a * vv);
}

// ---------------------------------------------------------------------------
// Final classifier: out = h[0] @ Wout + bout
// ---------------------------------------------------------------------------
__global__ __launch_bounds__(256) void final_kernel(const float* __restrict__ h0,
        const float* __restrict__ Wout, const float* __restrict__ bout,
        float* __restrict__ out) {
    __shared__ float w[128 * 16];
    __shared__ float hs[16][132];
    for (int i = threadIdx.x; i < 128 * 16; i += 256) w[i] = Wout[i];
    int row0 = blockIdx.x * 16;
    for (int i = threadIdx.x; i < 16 * 128; i += 256) {
        int rr = i >> 7, kk = i & 127;
        int rg = row0 + rr; if (rg >= NN) rg = NN - 1;
        hs[rr][kk] = h0[(size_t)rg * 128 + kk];
    }
    __syncthreads();
    int rr = threadIdx.x >> 4, colc = threadIdx.x & 15;
    float s = bout[colc];
    #pragma unroll 8
    for (int k = 0; k < 128; k++) s += hs[rr][k] * w[k * 16 + colc];
    int rg = row0 + rr;
    if (rg < NN) out[(size_t)rg * 16 + colc] = s;
}

// ---------------------------------------------------------------------------
extern "C" void kernel_launch(void* const* d_in, const int* in_sizes, int n_in,
                              void* d_out, int out_size, void* d_ws, size_t ws_size,
                              hipStream_t stream) {
    const float* x        = (const float*)d_in[0];
    const int*   edge_src = (const int*)d_in[1];
    const int*   edge_dst = (const int*)d_in[2];
    const int*   rel_src  = (const int*)d_in[3];
    const int*   rel_dst  = (const int*)d_in[4];
    const float* Wenc     = (const float*)d_in[5];
    const float* benc     = (const float*)d_in[6];
    const float* Wk       = (const float*)d_in[7];
    const float* bk       = (const float*)d_in[8];
    const float* Wq       = (const float*)d_in[9];
    const float* bq       = (const float*)d_in[10];
    const float* Wv       = (const float*)d_in[11];
    const float* bv       = (const float*)d_in[12];
    const float* Wa       = (const float*)d_in[13];
    const float* ba       = (const float*)d_in[14];
    const float* skip     = (const float*)d_in[15];
    const float* a_rel    = (const float*)d_in[16];
    const float* m_rel    = (const float*)d_in[17];
    const float* p_rel    = (const float*)d_in[18];
    const float* Wout     = (const float*)d_in[19];
    const float* bout     = (const float*)d_in[20];
    float* out = (float*)d_out;
    float* wsf = (float*)d_ws;

    // workspace (floats): h + buf1(qa/va chunks, <=8 relations = TNH) + buf2(k/agg)
    //                     + alpha + stats + CSR + folded weights
    const size_t NEED_FLOATS = 3 * TNH + (size_t)RE * NHEADS + 2 * (size_t)RN * NHEADS
                             + 3 * (size_t)RN + 2 * (size_t)RE
                             + 2 * (size_t)RR * HH * HH + 2 * (size_t)RR * HH + 256;
    if (ws_size < NEED_FLOATS * sizeof(float)) {
        zero_kernel<<<313, 256, 0, stream>>>((float4*)out, out_size / 4);
        return;
    }
    float* h    = wsf;
    float* buf1 = h    + TNH;          // qa chunk, then va chunk (8 rel = TNH max)
    float* buf2 = buf1 + TNH;          // k, then agg
    float* alpha = buf2 + TNH;
    float* mbuf  = alpha + (size_t)RE * NHEADS;
    float* dbuf  = mbuf + (size_t)RN * NHEADS;
    float* Wqa   = dbuf + (size_t)RN * NHEADS;
    float* Wva   = Wqa + (size_t)RR * HH * HH;
    float* bqa   = Wva + (size_t)RR * HH * HH;
    float* bva   = bqa + (size_t)RR * HH;
    int* cnt     = (int*)(bva + (size_t)RR * HH);
    int* ofs     = cnt + RN;
    int* cursor  = ofs + RN;
    int* pos_src = cursor + RN;
    int* pos_seg = pos_src + RE;
    int* bsum    = pos_seg + RE;

    const int RB = (NN + 127) / 128;   // 157 row blocks
    const int C1 = 8, C2 = RR - C1;    // relation chunks (8 + 4)
    const int P1 = C1 * EE;            // CSR positions of chunk 1

    // ---- CSR build (shared by both layers) ----
    zero_kernel<<<235, 256, 0, stream>>>((float4*)cnt, RN / 4);
    hist_kernel<<<(RE + 255) / 256, 256, 0, stream>>>(edge_dst, cnt);
    int nb = (RN + 1023) / 1024;       // 235
    scan_local<<<nb, 256, 0, stream>>>(cnt, ofs, bsum, RN);
    scan_bsum<<<1, 256, 0, stream>>>(bsum, nb);
    scan_add<<<(RN + 255) / 256, 256, 0, stream>>>(ofs, cursor, bsum, RN);
    scatter_kernel<<<(RE + 255) / 256, 256, 0, stream>>>(edge_dst, edge_src,
                                                         cursor, pos_src, pos_seg);

    // ---- encoder: h = relu(x @ Wenc + benc) ----
    {
        Jobs8 je;
        for (int t = 0; t < 8; t++)
            je.j[t] = { x + t * NH_, Wenc + (size_t)t * 128 * 128, benc + t * 128, h + t * NH_ };
        gemm128<1, Jobs8><<<dim3(RB, 8), 256, 0, stream>>>(je, nullptr);
    }

    // ---- layers ----
    for (int l = 0; l < LL; l++) {
        const float* prel_l = p_rel + (size_t)l * RR * NHEADS;

        // folded per-relation weights
        weff_kernel<<<RR, 256, 0, stream>>>(rel_src, rel_dst, Wq, bq, Wv, bv,
                a_rel + (size_t)l * RR * NHEADS * DD * DD,
                m_rel + (size_t)l * RR * NHEADS * DD * DD,
                l, Wqa, bqa, Wva, bva);

        // k -> buf2 (type space)
        Jobs8 jk;
        for (int t = 0; t < 8; t++) {
            size_t wi = (size_t)(l * TT + t) * 128 * 128;
            size_t bi = (size_t)(l * TT + t) * 128;
            jk.j[t] = { h + t * NH_, Wk + wi, bk + bi, buf2 + t * NH_ };
        }
        gemm128<0, Jobs8><<<dim3(RB, 8), 256, 0, stream>>>(jk, nullptr);

        // qa chunk 1 (relations 0..7) -> buf1; score those edges
        gemm128_rel<<<dim3(RB, C1), 256, 0, stream>>>(h, rel_dst, 0, Wqa, bqa, buf1);
        score_kernel<<<P1 / 2, 256, 0, stream>>>(pos_src, pos_seg, rel_src, 0, 0,
                                                 buf1, buf2, prel_l, alpha);
        // qa chunk 2 (relations 8..11)
        gemm128_rel<<<dim3(RB, C2), 256, 0, stream>>>(h, rel_dst, C1, Wqa, bqa, buf1);
        score_kernel<<<(RE - P1) / 2, 256, 0, stream>>>(pos_src, pos_seg, rel_src, P1, C1,
                                                        buf1, buf2, prel_l, alpha);

        // per-(seg,head) softmax stats
        stats_kernel<<<(RN * NHEADS + 255) / 256, 256, 0, stream>>>(ofs, cnt, alpha, mbuf, dbuf);

        // agg -> buf2 (k dead after score): zero then accumulate
        zero_kernel<<<2048, 256, 0, stream>>>((float4*)buf2, (int)(TNH / 4));

        // va chunk 1 -> buf1; aggregate those edges
        gemm128_rel<<<dim3(RB, C1), 256, 0, stream>>>(h, rel_src, 0, Wva, bva, buf1);
        aggregate_kernel<<<P1 / 2, 256, 0, stream>>>(pos_src, pos_seg, rel_dst, 0, 0,
                                                     buf1, alpha, mbuf, dbuf, buf2);
        // va chunk 2
        gemm128_rel<<<dim3(RB, C2), 256, 0, stream>>>(h, rel_src, C1, Wva, bva, buf1);
        aggregate_kernel<<<(RE - P1) / 2, 256, 0, stream>>>(pos_src, pos_seg, rel_dst, P1, C1,
                                                            buf1, alpha, mbuf, dbuf, buf2);

        // out-proj + skip blend (gelu(agg) @ Wa, blend into h)
        Jobs8 jo;
        for (int t = 0; t < 8; t++) {
            size_t wi = (size_t)(l * TT + t) * 128 * 128;
            size_t bi = (size_t)(l * TT + t) * 128;
            jo.j[t] = { buf2 + t * NH_, Wa + wi, ba + bi, h + t * NH_ };
        }
        gemm128<2, Jobs8><<<dim3(RB, 8), 256, 0, stream>>>(jo, skip + l * TT);
    }

    // ---- classifier ----
    final_kernel<<<NN / 16, 256, 0, stream>>>(h, Wout, bout, out);
}